// Round 7
// baseline (1694.555 us; speedup 1.0000x reference)
//
#include <hip/hip_runtime.h>
#include <math.h>

// ---------------------------------------------------------------------------
// MultiViewEPSSClassifier forward. N=50000, E=600000, IN=512, H=128, B=64, L=4.
// R2: atomic scatter -> CSR gather.   R3: atomic-free pooling; fused GRU GEMM.
// R4: ggnn_w folded into GRU weights; GRU GEMM -> MFMA bf16.
// R5: parallel classifier; proj/attn MFMA; bcast removed.
// R6: bf16 state pipeline (gather bf16, single-pass bf16 A).
// R7: gate-SEPARATED B layout: acc[g] holds all 4 gates for the same (row,ch)
//     -> GRU epilogue is pure per-lane register math (0 shuffles, coalesced
//     stores); skip zero gate-halves (n has no hh rows, h no ih rows): 25%
//     less MFMA+B traffic; 64rx128ch blocks (A read once, no y-split);
//     gather 16 lanes/row ushort8.
// ---------------------------------------------------------------------------

typedef __attribute__((ext_vector_type(8))) short short8;
typedef __attribute__((ext_vector_type(4))) float floatx4;

__device__ __forceinline__ unsigned short f2bf_rtn(float x) {
    unsigned u = __float_as_uint(x);
    return (unsigned short)((u + 0x7FFFu + ((u >> 16) & 1u)) >> 16);
}
__device__ __forceinline__ float bf2f(unsigned short h) {
    return __uint_as_float((unsigned)h << 16);
}

// types {0,9,10}->0, {1,2,3}->1, {4,5,6}->2, {7,8,11,12}->3 (partition of 0..12)
__device__ __forceinline__ int view_of(int t) {
    return (t >= 1 && t <= 3) ? 1 : (t >= 4 && t <= 6) ? 2
         : ((t == 7) || (t == 8) || (t >= 11)) ? 3 : 0;
}

// ----------------- fp32 GEMM (Wcomb precompute only, tiny) -----------------
template <bool BT, int EPI>
__global__ __launch_bounds__(256, 2) void gemm_k(
    const float* __restrict__ A, const float* __restrict__ Bm,
    const float* __restrict__ bias, float* __restrict__ C,
    int N, int M, int K, long sA, long sB, long sC)
{
    __shared__ float As[32][132];
    __shared__ float Bs[32][132];
    A  += (long)blockIdx.z * sA;
    Bm += (long)blockIdx.z * sB;
    C  += (long)blockIdx.z * sC;
    const int r0 = blockIdx.x * 128;
    const int c0 = blockIdx.y * 128;
    const int tid = threadIdx.x;
    const int tx = tid & 15;
    const int ty = tid >> 4;

    float acc[8][8];
#pragma unroll
    for (int i = 0; i < 8; i++)
#pragma unroll
        for (int j = 0; j < 8; j++) acc[i][j] = 0.0f;

    for (int k0 = 0; k0 < K; k0 += 32) {
        {
            int arow = tid >> 3;
            int akq  = (tid & 7) << 2;
#pragma unroll
            for (int hh = 0; hh < 4; hh++) {
                int r  = arow + hh * 32;
                int gr = r0 + r;
                float4 av = make_float4(0.f, 0.f, 0.f, 0.f);
                if (gr < N) av = *(const float4*)(A + (long)gr * K + k0 + akq);
                As[akq + 0][r] = av.x; As[akq + 1][r] = av.y;
                As[akq + 2][r] = av.z; As[akq + 3][r] = av.w;
            }
        }
        if (BT) {
            int brow = tid >> 3;
            int bkq  = (tid & 7) << 2;
#pragma unroll
            for (int hh = 0; hh < 4; hh++) {
                int r = brow + hh * 32;
                float4 bv = *(const float4*)(Bm + (long)(c0 + r) * K + k0 + bkq);
                Bs[bkq + 0][r] = bv.x; Bs[bkq + 1][r] = bv.y;
                Bs[bkq + 2][r] = bv.z; Bs[bkq + 3][r] = bv.w;
            }
        } else {
            int kk0 = tid >> 5;
            int bmq = (tid & 31) << 2;
#pragma unroll
            for (int hh = 0; hh < 4; hh++) {
                int kk = kk0 + hh * 8;
                float4 bv = *(const float4*)(Bm + (long)(k0 + kk) * M + c0 + bmq);
                *(float4*)&Bs[kk][bmq] = bv;
            }
        }
        __syncthreads();
#pragma unroll
        for (int k = 0; k < 32; k++) {
            float4 a0 = *(const float4*)&As[k][ty << 2];
            float4 a1 = *(const float4*)&As[k][64 + (ty << 2)];
            float4 b0 = *(const float4*)&Bs[k][tx << 2];
            float4 b1 = *(const float4*)&Bs[k][64 + (tx << 2)];
            float av[8] = {a0.x, a0.y, a0.z, a0.w, a1.x, a1.y, a1.z, a1.w};
            float bv[8] = {b0.x, b0.y, b0.z, b0.w, b1.x, b1.y, b1.z, b1.w};
#pragma unroll
            for (int i = 0; i < 8; i++)
#pragma unroll
                for (int j = 0; j < 8; j++) acc[i][j] += av[i] * bv[j];
        }
        __syncthreads();
    }

    float bb[8] = {0, 0, 0, 0, 0, 0, 0, 0};
    if (bias) {
        float4 b0 = *(const float4*)(bias + c0 + (tx << 2));
        float4 b1 = *(const float4*)(bias + c0 + 64 + (tx << 2));
        bb[0] = b0.x; bb[1] = b0.y; bb[2] = b0.z; bb[3] = b0.w;
        bb[4] = b1.x; bb[5] = b1.y; bb[6] = b1.z; bb[7] = b1.w;
    }
#pragma unroll
    for (int i = 0; i < 8; i++) {
        int r = (i < 4) ? (r0 + (ty << 2) + i) : (r0 + 64 + (ty << 2) + i - 4);
        if (r < N) {
            float v[8];
#pragma unroll
            for (int j = 0; j < 8; j++) {
                v[j] = acc[i][j] + bb[j];
                if (EPI == 1) v[j] = tanhf(v[j]);
            }
            *(float4*)(C + (long)r * M + c0 + (tx << 2)) = make_float4(v[0], v[1], v[2], v[3]);
            *(float4*)(C + (long)r * M + c0 + 64 + (tx << 2)) = make_float4(v[4], v[5], v[6], v[7]);
        }
    }
}

// ---------- build P_ih_rep[16][128][512], P_hh[4][128][512], bias ----------
// matrices keep interleaved col = ch*4+g (for the fold GEMM); bias is stored
// gate-separated: bp[v][g*128+ch].
__global__ __launch_bounds__(256) void build_p_k(
    const float* __restrict__ gwih, const float* __restrict__ gwhh,
    const float* __restrict__ gbih, const float* __restrict__ gbhh,
    float* __restrict__ pih, float* __restrict__ phh, float* __restrict__ bp)
{
    int idx = blockIdx.x * 256 + threadIdx.x;
    if (idx < 16 * 65536) {
        int z = idx >> 16, rem = idx & 65535;
        int k = rem >> 9, mcol = rem & 511;
        int ch = mcol >> 2, g = mcol & 3;
        int v = z >> 2;
        const float* Wih = gwih + (long)v * 384 * 128;
        float val = 0.0f;
        if (g == 0) val = Wih[ch * 128 + k];
        else if (g == 1) val = Wih[(128 + ch) * 128 + k];
        else if (g == 2) val = Wih[(256 + ch) * 128 + k];
        pih[idx] = val;
    }
    if (idx < 4 * 65536) {
        int v = idx >> 16, rem = idx & 65535;
        int k = rem >> 9, mcol = rem & 511;
        int ch = mcol >> 2, g = mcol & 3;
        const float* Whh = gwhh + (long)v * 384 * 128;
        float val = 0.0f;
        if (g == 0) val = Whh[ch * 128 + k];
        else if (g == 1) val = Whh[(128 + ch) * 128 + k];
        else if (g == 3) val = Whh[(256 + ch) * 128 + k];
        phh[idx] = val;
    }
    if (idx < 4 * 512) {
        int v = idx >> 9, mcol = idx & 511;
        int ch = mcol >> 2, g = mcol & 3;
        float val;
        if (g == 0) val = gbih[v * 384 + ch] + gbhh[v * 384 + ch];
        else if (g == 1) val = gbih[v * 384 + 128 + ch] + gbhh[v * 384 + 128 + ch];
        else if (g == 2) val = gbih[v * 384 + 256 + ch];
        else val = gbhh[v * 384 + 256 + ch];
        bp[v * 512 + g * 128 + ch] = val;   // gate-separated
    }
}

// ---- pack GRU weights -> gate-separated bf16 frags -----------------------
// Bp[z][g][ks][ch][t], t = q*8+j (k = ks*32 + t), col source = ch*4+g.
__global__ __launch_bounds__(256) void pack_b_k(
    const float* __restrict__ wcomb, const float* __restrict__ phh,
    short* __restrict__ Bp)
{
    int idx = blockIdx.x * 256 + threadIdx.x;
    if (idx >= 16 * 131072) return;
    int z = idx >> 17, rem = idx & 131071;
    int t  = rem & 31;
    int ch = (rem >> 5) & 127;
    int ks = (rem >> 12) & 7;
    int g  = rem >> 15;
    int k = ks * 32 + t;
    int col = ch * 4 + g;
    float val = (k < 128) ? wcomb[(long)z * 65536 + k * 512 + col]
                          : phh[(long)(z >> 2) * 65536 + (k - 128) * 512 + col];
    Bp[idx] = (short)f2bf_rtn(val);
}

// ---- pack fp32 weight [K][128] (or transposed [128][K]) -> bf16 hi/lo -----
template <bool BT>
__global__ __launch_bounds__(256) void pack_w_k(
    const float* __restrict__ W, short* __restrict__ bhi, short* __restrict__ blo, int K)
{
    int idx = blockIdx.x * 256 + threadIdx.x;
    if (idx >= K * 128) return;
    int k = idx >> 7, col = idx & 127;
    float v = BT ? W[col * K + k] : W[k * 128 + col];
    unsigned short h = f2bf_rtn(v);
    float fh = __uint_as_float((unsigned)h << 16);
    long dst = ((long)(k >> 5) * 128 + col) * 32 + ((k >> 3) & 3) * 8 + (k & 7);
    bhi[dst] = (short)h;
    blo[dst] = (short)f2bf_rtn(v - fh);
}

// ------------- MFMA GEMM: C[N,128] = A[N,K]@W + bias, 3-pass ---------------
template <int EPI>
__global__ __launch_bounds__(256, 4) void gemm_mfma_k(
    const float* __restrict__ A, const short* __restrict__ Bhi,
    const short* __restrict__ Blo, const float* __restrict__ bias,
    float* __restrict__ C, int N, int K)
{
    __shared__ __align__(16) short Ahi[64 * 40];
    __shared__ __align__(16) short Alo[64 * 40];
    const int r0 = blockIdx.x * 64;
    const int tid = threadIdx.x;
    const int l = tid & 63, w = tid >> 6;
    const int wrow = w * 16;
    const int m = l & 15, q = l >> 4;

    floatx4 acc[8];
#pragma unroll
    for (int b = 0; b < 8; b++) acc[b] = (floatx4)0.0f;

    const int arow = tid >> 2;
    const int fcol = (tid & 3) * 8;
    const int gr = r0 + arow;
    const int nks = K >> 5;

    for (int ks = 0; ks < nks; ks++) {
        float xv[8];
        if (gr < N) {
            float4 x0 = *(const float4*)(A + (long)gr * K + ks * 32 + fcol);
            float4 x1 = *(const float4*)(A + (long)gr * K + ks * 32 + fcol + 4);
            xv[0] = x0.x; xv[1] = x0.y; xv[2] = x0.z; xv[3] = x0.w;
            xv[4] = x1.x; xv[5] = x1.y; xv[6] = x1.z; xv[7] = x1.w;
        } else {
#pragma unroll
            for (int u = 0; u < 8; u++) xv[u] = 0.0f;
        }
        short8 vhi, vlo;
#pragma unroll
        for (int u = 0; u < 8; u++) {
            unsigned short hb = f2bf_rtn(xv[u]);
            float fh = __uint_as_float((unsigned)hb << 16);
            vhi[u] = (short)hb;
            vlo[u] = (short)f2bf_rtn(xv[u] - fh);
        }
        *(short8*)&Ahi[arow * 40 + fcol] = vhi;
        *(short8*)&Alo[arow * 40 + fcol] = vlo;
        __syncthreads();
        short8 ah = *(short8*)&Ahi[(wrow + m) * 40 + q * 8];
        short8 al = *(short8*)&Alo[(wrow + m) * 40 + q * 8];
#pragma unroll
        for (int tn = 0; tn < 8; tn++) {
            int col = tn * 16 + m;
            short8 bh = *(const short8*)(Bhi + ((long)ks * 128 + col) * 32 + q * 8);
            short8 bl = *(const short8*)(Blo + ((long)ks * 128 + col) * 32 + q * 8);
            acc[tn] = __builtin_amdgcn_mfma_f32_16x16x32_bf16(ah, bh, acc[tn], 0, 0, 0);
            acc[tn] = __builtin_amdgcn_mfma_f32_16x16x32_bf16(al, bh, acc[tn], 0, 0, 0);
            acc[tn] = __builtin_amdgcn_mfma_f32_16x16x32_bf16(ah, bl, acc[tn], 0, 0, 0);
        }
        __syncthreads();
    }

#pragma unroll
    for (int tn = 0; tn < 8; tn++) {
        int col = tn * 16 + m;
        float bb = bias ? bias[col] : 0.0f;
#pragma unroll
        for (int reg = 0; reg < 4; reg++) {
            int row = r0 + wrow + q * 4 + reg;
            if (row < N) {
                float v = acc[tn][reg] + bb;
                if (EPI == 1) v = tanhf(v);
                C[(long)row * 128 + col] = v;
            }
        }
    }
}

// -------------- MFMA fused GRU GEMM: h_next = GRU(S, h_cur) ----------------
// Gate-separated B: Bp[z][g][ks][ch][32]. Block 64 rows x 128 ch (all gates),
// 4 waves of 32r x 64ch. acc[g][tm*4+tn] holds all 4 gates for this lane's
// (row,ch) -> pure-register GRU epilogue, coalesced stores. Gate n (g=2) has
// zero hh rows (skip ks>=4); gate h (g=3) zero ih rows (skip ks<4).
__global__ __launch_bounds__(256, 3) void gemm_gru_mfma_k(
    const short* __restrict__ Sb, const short* __restrict__ hb,
    const float* __restrict__ hpf, const short* __restrict__ Bp,
    const float* __restrict__ bp, float* __restrict__ hf,
    short* __restrict__ hbn, int N, long sV, long sHb, long sHp)
{
    __shared__ __align__(16) short As[64 * 40];
    const int z = blockIdx.z;
    Sb  += (long)z * sV;
    hb  += (long)z * sHb;
    hpf += (long)z * sHp;
    Bp  += (long)z * 524288;
    bp  += (long)z * 512;
    hf  += (long)z * sV;
    hbn += (long)z * sV;
    const int r0 = blockIdx.x * 64;
    const int tid = threadIdx.x;
    const int l = tid & 63, w = tid >> 6;
    const int wrow = (w & 1) * 32;
    const int wch  = (w >> 1) * 64;
    const int m = l & 15, q = l >> 4;

    floatx4 acc[4][8];   // [gate][tm*4+tn]
#pragma unroll
    for (int g = 0; g < 4; g++)
#pragma unroll
        for (int b = 0; b < 8; b++) acc[g][b] = (floatx4)0.0f;

    const int arow = tid >> 2;
    const int fcol = (tid & 3) * 8;
    const int gr = r0 + arow;

    for (int ks = 0; ks < 8; ks++) {
        const short* asrc = (ks < 4) ? Sb : hb;
        const int koff = (ks & 3) * 32 + fcol;
        short8 av = (short8)0;
        if (gr < N) av = *(const short8*)(asrc + (long)gr * 128 + koff);
        *(short8*)&As[arow * 40 + fcol] = av;
        __syncthreads();
        short8 a0 = *(short8*)&As[(wrow + m) * 40 + q * 8];
        short8 a1 = *(short8*)&As[(wrow + 16 + m) * 40 + q * 8];
#pragma unroll
        for (int tn = 0; tn < 4; tn++) {
            int col = wch + tn * 16 + m;
            const short* bb = Bp + ((long)ks * 128 + col) * 32 + q * 8;
            // g=0 (r) and g=1 (z): full K
            short8 b0 = *(const short8*)(bb);
            short8 b1 = *(const short8*)(bb + 32768);
            acc[0][tn]     = __builtin_amdgcn_mfma_f32_16x16x32_bf16(a0, b0, acc[0][tn], 0, 0, 0);
            acc[0][4 + tn] = __builtin_amdgcn_mfma_f32_16x16x32_bf16(a1, b0, acc[0][4 + tn], 0, 0, 0);
            acc[1][tn]     = __builtin_amdgcn_mfma_f32_16x16x32_bf16(a0, b1, acc[1][tn], 0, 0, 0);
            acc[1][4 + tn] = __builtin_amdgcn_mfma_f32_16x16x32_bf16(a1, b1, acc[1][4 + tn], 0, 0, 0);
            // g=2 (n): ih half only; g=3 (h): hh half only
            int gsel = (ks < 4) ? 2 : 3;
            short8 b2 = *(const short8*)(bb + gsel * 32768);
            acc[gsel][tn]     = __builtin_amdgcn_mfma_f32_16x16x32_bf16(a0, b2, acc[gsel][tn], 0, 0, 0);
            acc[gsel][4 + tn] = __builtin_amdgcn_mfma_f32_16x16x32_bf16(a1, b2, acc[gsel][4 + tn], 0, 0, 0);
        }
        __syncthreads();
    }

    // ---- GRU epilogue: all 4 gates in-register per (row,ch) ----
#pragma unroll
    for (int tn = 0; tn < 4; tn++) {
        const int ch = wch + tn * 16 + m;
        float brv = bp[ch];
        float bzv = bp[128 + ch];
        float bnv = bp[256 + ch];
        float bhv = bp[384 + ch];
#pragma unroll
        for (int tm = 0; tm < 2; tm++) {
#pragma unroll
            for (int reg = 0; reg < 4; reg++) {
                int row = r0 + wrow + tm * 16 + q * 4 + reg;
                if (row < N) {
                    float hp = hpf[(long)row * 128 + ch];
                    float vr = acc[0][tm * 4 + tn][reg];
                    float vz = acc[1][tm * 4 + tn][reg];
                    float vn = acc[2][tm * 4 + tn][reg];
                    float vh = acc[3][tm * 4 + tn][reg];
                    float rr = 1.0f / (1.0f + expf(-(vr + brv)));
                    float zz = 1.0f / (1.0f + expf(-(vz + bzv)));
                    float nn = tanhf(vn + bnv + rr * (vh + bhv));
                    float hnv = (1.0f - zz) * nn + zz * hp;
                    hf[(long)row * 128 + ch] = hnv;
                    hbn[(long)row * 128 + ch] = (short)f2bf_rtn(hnv);
                }
            }
        }
    }
}

// ------------- LayerNorm + GELU (in-place) + bf16 copy out -----------------
__global__ __launch_bounds__(256) void ln_gelu_k(
    float* __restrict__ h0, short* __restrict__ h0b,
    const float* __restrict__ w, const float* __restrict__ b, int N)
{
    long t = (long)blockIdx.x * 256 + threadIdx.x;
    int n = (int)(t >> 5), lane = (int)(t & 31);
    if (n >= N) return;
    float* p = h0 + (long)n * 128 + lane * 4;
    float4 x = *(float4*)p;
    float s = x.x + x.y + x.z + x.w;
#pragma unroll
    for (int off = 16; off >= 1; off >>= 1) s += __shfl_xor(s, off);
    float mu = s * (1.0f / 128.0f);
    float4 d = make_float4(x.x - mu, x.y - mu, x.z - mu, x.w - mu);
    float ss = d.x * d.x + d.y * d.y + d.z * d.z + d.w * d.w;
#pragma unroll
    for (int off = 16; off >= 1; off >>= 1) ss += __shfl_xor(ss, off);
    float inv = 1.0f / sqrtf(ss * (1.0f / 128.0f) + 1e-5f);
    float4 wv = *(const float4*)(w + lane * 4);
    float4 bv = *(const float4*)(b + lane * 4);
    float y[4] = {d.x * inv * wv.x + bv.x, d.y * inv * wv.y + bv.y,
                  d.z * inv * wv.z + bv.z, d.w * inv * wv.w + bv.w};
#pragma unroll
    for (int i = 0; i < 4; i++)
        y[i] = 0.5f * y[i] * (1.0f + erff(y[i] * 0.70710678118654752f));
    *(float4*)p = make_float4(y[0], y[1], y[2], y[3]);
    ushort4 hb;
    hb.x = f2bf_rtn(y[0]); hb.y = f2bf_rtn(y[1]);
    hb.z = f2bf_rtn(y[2]); hb.w = f2bf_rtn(y[3]);
    *(ushort4*)(h0b + (long)n * 128 + lane * 4) = hb;
}

// ------------------------------ CSR build ----------------------------------
__global__ __launch_bounds__(256) void count_k(
    const int* __restrict__ dst, const int* __restrict__ et,
    int* __restrict__ cnt, int E, int N)
{
    int e = blockIdx.x * 256 + threadIdx.x;
    if (e >= E) return;
    int v = view_of(et[e]);
    atomicAdd(&cnt[v * N + dst[e]], 1);
}

__global__ __launch_bounds__(256) void scan1_k(
    const int* __restrict__ cnt, int* __restrict__ off, int* __restrict__ bsum, int n)
{
    __shared__ int sm[256];
    int base = blockIdx.x * 1024;
    int tid = threadIdx.x;
    int v[4]; int s = 0;
#pragma unroll
    for (int i = 0; i < 4; i++) {
        int idx = base + tid * 4 + i;
        v[i] = (idx < n) ? cnt[idx] : 0; s += v[i];
    }
    sm[tid] = s; __syncthreads();
    for (int o = 1; o < 256; o <<= 1) {
        int t2 = (tid >= o) ? sm[tid - o] : 0;
        __syncthreads(); sm[tid] += t2; __syncthreads();
    }
    int run = sm[tid] - s;
    if (tid == 255) bsum[blockIdx.x] = sm[255];
#pragma unroll
    for (int i = 0; i < 4; i++) {
        int idx = base + tid * 4 + i;
        if (idx < n) off[idx] = run;
        run += v[i];
    }
}

__global__ __launch_bounds__(256) void scan2_k(int* __restrict__ bsum, int nb)
{
    __shared__ int sm[256];
    int tid = threadIdx.x;
    int v = (tid < nb) ? bsum[tid] : 0;
    sm[tid] = v; __syncthreads();
    for (int o = 1; o < 256; o <<= 1) {
        int t2 = (tid >= o) ? sm[tid - o] : 0;
        __syncthreads(); sm[tid] += t2; __syncthreads();
    }
    if (tid < nb) bsum[tid] = sm[tid] - v;
}

__global__ __launch_bounds__(256) void scan3_k(
    int* __restrict__ off, int* __restrict__ cursor,
    const int* __restrict__ bsum, int n, int total)
{
    int i = blockIdx.x * 256 + threadIdx.x;
    if (i < n) {
        int o = off[i] + bsum[i >> 10];
        off[i] = o; cursor[i] = o;
    }
    if (i == 0) off[n] = total;
}

__global__ __launch_bounds__(256) void fill_k(
    const int* __restrict__ src, const int* __restrict__ dst,
    const int* __restrict__ et, int* __restrict__ cursor,
    int* __restrict__ esrc, int* __restrict__ esrc0, int E, int N)
{
    int e = blockIdx.x * 256 + threadIdx.x;
    if (e >= E) return;
    int v = view_of(et[e]);
    int b = v * N + dst[e];
    int pos = atomicAdd(&cursor[b], 1);
    esrc[pos] = v * N + src[e];
    esrc0[pos] = src[e];
}

// --------- CSR gather (bf16, 16 lanes/row): S[r] = sum h[esrc[j]] ----------
__global__ __launch_bounds__(256) void gather_bf_k(
    const short* __restrict__ hb, short* __restrict__ Sb,
    const int* __restrict__ off, const int* __restrict__ esrc, int R)
{
    long t = (long)blockIdx.x * 256 + threadIdx.x;
    int r = (int)(t >> 4), lane = (int)(t & 15);
    if (r >= R) return;
    int beg = off[r], end = off[r + 1];
    float a[8] = {0.f, 0.f, 0.f, 0.f, 0.f, 0.f, 0.f, 0.f};
    for (int j = beg; j < end; j++) {
        int s = esrc[j];
        short8 v = *(const short8*)(hb + (long)s * 128 + lane * 8);
#pragma unroll
        for (int u = 0; u < 8; u++) a[u] += bf2f((unsigned short)v[u]);
    }
    short8 o;
#pragma unroll
    for (int u = 0; u < 8; u++) o[u] = (short)f2bf_rtn(a[u]);
    *(short8*)(Sb + (long)r * 128 + lane * 8) = o;
}

// -------------------- per-view LayerNorm + residual (in-place) -------------
__global__ __launch_bounds__(256) void vln_res_k(
    float* __restrict__ h, const float* __restrict__ h0,
    const float* __restrict__ w, const float* __restrict__ b, int N)
{
    int v = blockIdx.z;
    long t = (long)blockIdx.x * 256 + threadIdx.x;
    int n = (int)(t >> 5), lane = (int)(t & 31);
    if (n >= N) return;
    float* hp = h + ((long)v * N + n) * 128 + lane * 4;
    float4 x = *(float4*)hp;
    float s = x.x + x.y + x.z + x.w;
#pragma unroll
    for (int off = 16; off >= 1; off >>= 1) s += __shfl_xor(s, off);
    float mu = s * (1.0f / 128.0f);
    float4 d = make_float4(x.x - mu, x.y - mu, x.z - mu, x.w - mu);
    float ss = d.x * d.x + d.y * d.y + d.z * d.z + d.w * d.w;
#pragma unroll
    for (int off = 16; off >= 1; off >>= 1) ss += __shfl_xor(ss, off);
    float inv = 1.0f / sqrtf(ss * (1.0f / 128.0f) + 1e-5f);
    float4 wv = *(const float4*)(w + v * 128 + lane * 4);
    float4 bv = *(const float4*)(b + v * 128 + lane * 4);
    float4 hv = *(const float4*)(h0 + (long)n * 128 + lane * 4);
    float4 r;
    r.x = d.x * inv * wv.x + bv.x + hv.x;
    r.y = d.y * inv * wv.y + bv.y + hv.y;
    r.z = d.z * inv * wv.z + bv.z + hv.z;
    r.w = d.w * inv * wv.w + bv.w + hv.w;
    *(float4*)hp = r;
}

// -------------- attention fusion (no atomics): fused[N,128] ----------------
__global__ __launch_bounds__(256) void fusion_k(
    const float* __restrict__ hs, const float* __restrict__ q,
    const float* __restrict__ u, const float* __restrict__ kb,
    float* __restrict__ fused, int N)
{
    long t = (long)blockIdx.x * 256 + threadIdx.x;
    int n = (int)(t >> 5), lane = (int)(t & 31);
    if (n >= N) return;
    long NH = (long)N * 128;
    float4 qv = *(const float4*)(q + (long)n * 128 + lane * 4);
    float4 kv = *(const float4*)(kb + lane * 4);
    float4 uv = *(const float4*)(u + (long)n * 128 + lane * 4);
    float part = qv.x * kv.x + qv.y * kv.y + qv.z * kv.z + qv.w * kv.w;
    float4 hv[4];
    float lg[4];
#pragma unroll
    for (int v = 0; v < 4; v++) {
        hv[v] = *(const float4*)(hs + v * NH + (long)n * 128 + lane * 4);
        lg[v] = hv[v].x * uv.x + hv[v].y * uv.y + hv[v].z * uv.z + hv[v].w * uv.w;
    }
#pragma unroll
    for (int off = 16; off >= 1; off >>= 1) {
        part += __shfl_xor(part, off);
#pragma unroll
        for (int v = 0; v < 4; v++) lg[v] += __shfl_xor(lg[v], off);
    }
    const float scale = 0.08838834764831845f;
    float mx = -1e30f;
#pragma unroll
    for (int v = 0; v < 4; v++) { lg[v] = (lg[v] + part) * scale; mx = fmaxf(mx, lg[v]); }
    float se = 0.0f;
#pragma unroll
    for (int v = 0; v < 4; v++) { lg[v] = expf(lg[v] - mx); se += lg[v]; }
    float inv = 1.0f / se;
    float4 f = make_float4(0.f, 0.f, 0.f, 0.f);
#pragma unroll
    for (int v = 0; v < 4; v++) {
        float a = lg[v] * inv;
        f.x += a * hv[v].x; f.y += a * hv[v].y; f.z += a * hv[v].z; f.w += a * hv[v].w;
    }
    *(float4*)(fused + (long)n * 128 + lane * 4) = f;
}

// ------------- pooling: one block per graph (batch is sorted) --------------
__global__ __launch_bounds__(256) void pool_k(
    const float* __restrict__ fused, const int* __restrict__ batch,
    float* __restrict__ meanb, float* __restrict__ maxb, int N)
{
    __shared__ float s_sum[256], s_max[256];
    int b = blockIdx.x;
    int lo = 0, hi = N;
    while (lo < hi) { int mid = (lo + hi) >> 1; if (batch[mid] < b) lo = mid + 1; else hi = mid; }
    int beg = lo;
    lo = beg; hi = N;
    while (lo < hi) { int mid = (lo + hi) >> 1; if (batch[mid] < b + 1) lo = mid + 1; else hi = mid; }
    int end = lo;
    int tid = threadIdx.x;
    int c = tid & 127, half = tid >> 7;
    float sum = 0.0f, mx = __int_as_float(0xff800000);
    for (int n = beg + half; n < end; n += 2) {
        float v = fused[(long)n * 128 + c];
        sum += v; mx = fmaxf(mx, v);
    }
    s_sum[tid] = sum; s_max[tid] = mx;
    __syncthreads();
    if (half == 0) {
        float tot = s_sum[tid] + s_sum[tid + 128];
        float m2 = fmaxf(s_max[tid], s_max[tid + 128]);
        int cnt = end - beg;
        meanb[b * 128 + c] = tot / (float)max(cnt, 1);
        maxb[b * 128 + c] = m2;
    }
}

// ---------------- classifier MLP: one block per graph (64 blocks) ----------
__global__ __launch_bounds__(256) void classifier_k(
    const float* __restrict__ meanb, const float* __restrict__ maxb,
    const float* __restrict__ c1w, const float* __restrict__ c1b,
    const float* __restrict__ c2w, const float* __restrict__ c2b,
    const float* __restrict__ c3w, const float* __restrict__ c3b,
    float* __restrict__ out)
{
    __shared__ float g[256];
    __shared__ float h1[128];
    __shared__ float h2[64];
    int b = blockIdx.x, tid = threadIdx.x;
    g[tid] = (tid < 128) ? meanb[b * 128 + tid] : maxb[b * 128 + (tid - 128)];
    __syncthreads();
    if (tid < 128) {
        float acc = c1b[tid];
        for (int k = 0; k < 256; k++) acc += g[k] * c1w[k * 128 + tid];
        h1[tid] = fmaxf(acc, 0.0f);
    }
    __syncthreads();
    if (tid < 64) {
        float acc = c2b[tid];
        for (int k = 0; k < 128; k++) acc += h1[k] * c2w[k * 64 + tid];
        h2[tid] = fmaxf(acc, 0.0f);
    }
    __syncthreads();
    if (tid < 64) {
        float p = h2[tid] * c3w[tid];
#pragma unroll
        for (int off = 32; off >= 1; off >>= 1) p += __shfl_xor(p, off);
        if (tid == 0) out[b] = c3b[0] + p;
    }
}

// ---------------------------------------------------------------------------
extern "C" void kernel_launch(void* const* d_in, const int* in_sizes, int n_in,
                              void* d_out, int out_size, void* d_ws, size_t ws_size,
                              hipStream_t stream) {
    (void)n_in; (void)out_size; (void)ws_size;
    const float* x      = (const float*)d_in[0];
    const int*   eidx   = (const int*)d_in[1];
    const int*   etype  = (const int*)d_in[2];
    const int*   batch  = (const int*)d_in[3];
    const float* proj_w = (const float*)d_in[4];
    const float* proj_b = (const float*)d_in[5];
    const float* ln0_w  = (const float*)d_in[6];
    const float* ln0_b  = (const float*)d_in[7];
    const float* ggnn_w = (const float*)d_in[8];
    const float* gwih   = (const float*)d_in[9];
    const float* gwhh   = (const float*)d_in[10];
    const float* gbih   = (const float*)d_in[11];
    const float* gbhh   = (const float*)d_in[12];
    const float* vln_w  = (const float*)d_in[13];
    const float* vln_b  = (const float*)d_in[14];
    const float* q_w    = (const float*)d_in[15];
    const float* q_b    = (const float*)d_in[16];
    const float* k_w    = (const float*)d_in[17];
    const float* k_b    = (const float*)d_in[18];
    const float* c1w    = (const float*)d_in[19];
    const float* c1b    = (const float*)d_in[20];
    const float* c2w    = (const float*)d_in[21];
    const float* c2b    = (const float*)d_in[22];
    const float* c3w    = (const float*)d_in[23];
    const float* c3b    = (const float*)d_in[24];
    float* out = (float*)d_out;

    const int N = in_sizes[3];
    const int E = in_sizes[2];
    const int IN = in_sizes[0] / N;
    const int H = 128, L = 4;
    const int N4 = 4 * N;

    long NH = (long)N * H;
    float* ws = (float*)d_ws;
    float* h0 = ws;                      // NH
    float* hf = h0 + NH;                 // 4*NH  (fp32 h, in-place across layers)
    float* poolMean = hf + 4 * NH;       // 8192
    float* poolMax  = poolMean + 8192;   // 8192
    float* bp = poolMax + 8192;          // 2048
    short* h0b = (short*)(bp + 2048);    // NH
    short* hbA = h0b + NH;               // 4*NH
    short* hbB = hbA + 4 * NH;           // 4*NH
    short* Sb  = hbB + 4 * NH;           // 4*NH
    short* Bp  = Sb + 4 * NH;            // 16*131072
    short* prjHi = Bp + 16 * 131072;     // 512*128
    short* prjLo = prjHi + 65536;
    short* qwHi  = prjLo + 65536;        // 128*128
    short* qwLo  = qwHi + 16384;
    short* kwHi  = qwLo + 16384;
    short* kwLo  = kwHi + 16384;
    int* iOff  = (int*)(kwLo + 16384);   // N4+1
    int* iCnt  = iOff + N4 + 1;
    int* iCur  = iCnt + N4;
    int* iBsum = iCur + N4;              // 256
    int* iEsrc  = iBsum + 256;           // E
    int* iEsrc0 = iEsrc + E;             // E
    // precompute overlays on hf (dead before layer 0 writes hf)
    float* wcomb = hf;                   // 16*65536
    float* pih   = hf + 16 * 65536;      // 16*65536
    float* phh   = pih + 16 * 65536;     // 4*65536
    // tail overlays (dead after last GRU)
    float* qbuf  = (float*)Sb;           // NH
    float* ubuf  = qbuf + NH;            // NH
    float* fused = (float*)hbA;          // NH

    int rb = (int)(((long)N * 32 + 255) / 256);
    int eb = (E + 255) / 256;
    int nbScan = (N4 + 1023) / 1024;
    int gx64 = (N + 63) / 64;

    const int* esrc_in = eidx;
    const int* edst_in = eidx + E;

    // ---- CSR build ----
    hipMemsetAsync(iCnt, 0, (size_t)N4 * sizeof(int), stream);
    count_k<<<eb, 256, 0, stream>>>(edst_in, etype, iCnt, E, N);
    scan1_k<<<nbScan, 256, 0, stream>>>(iCnt, iOff, iBsum, N4);
    scan2_k<<<1, 256, 0, stream>>>(iBsum, nbScan);
    scan3_k<<<(N4 + 255) / 256, 256, 0, stream>>>(iOff, iCur, iBsum, N4, E);
    fill_k<<<eb, 256, 0, stream>>>(esrc_in, edst_in, etype, iCur, iEsrc, iEsrc0, E, N);

    // ---- GRU weight fold + bf16 packs (once per call) ----
    build_p_k<<<(16 * 65536 + 255) / 256, 256, 0, stream>>>(
        gwih, gwhh, gbih, gbhh, pih, phh, bp);
    gemm_k<false, 0><<<dim3(1, 4, 16), 256, 0, stream>>>(
        ggnn_w, pih, nullptr, wcomb, 128, 512, 128,
        (long)H * H, 65536, 65536);
    pack_b_k<<<(16 * 131072 + 255) / 256, 256, 0, stream>>>(wcomb, phh, Bp);
    pack_w_k<false><<<(IN * 128 + 255) / 256, 256, 0, stream>>>(proj_w, prjHi, prjLo, IN);
    pack_w_k<false><<<(128 * 128 + 255) / 256, 256, 0, stream>>>(q_w, qwHi, qwLo, 128);
    pack_w_k<true><<<(128 * 128 + 255) / 256, 256, 0, stream>>>(k_w, kwHi, kwLo, 128);

    // ---- input projection (MFMA 3-pass) + LN + GELU (+bf16 copy) ----
    gemm_mfma_k<0><<<gx64, 256, 0, stream>>>(x, prjHi, prjLo, proj_b, h0, N, IN);
    ln_gelu_k<<<rb, 256, 0, stream>>>(h0, h0b, ln0_w, ln0_b, N);

    // ---- 4 GGNN layers: bf16 gather -> gate-separated MFMA GRU ----
    const float* hpf = h0;   long sHp = 0;
    const short* hbc = h0b;  long sHb = 0;
    short* hbn = hbA;
    for (int i = 0; i < L; i++) {
        const int* es = (i == 0) ? iEsrc0 : iEsrc;
        gather_bf_k<<<(int)(((long)N4 * 16 + 255) / 256), 256, 0, stream>>>(
            hbc, Sb, iOff, es, N4);
        gemm_gru_mfma_k<<<dim3(gx64, 1, 4), 256, 0, stream>>>(
            Sb, hbc, hpf, Bp + (long)i * 131072, bp, hf, hbn, N, NH, sHb, sHp);
        hpf = hf; sHp = NH;
        hbc = hbn; sHb = NH;
        hbn = (hbn == hbA) ? hbB : hbA;
    }

    // ---- per-view LN + residual (hf becomes hs) ----
    vln_res_k<<<dim3(rb, 1, 4), 256, 0, stream>>>(hf, h0, vln_w, vln_b, N);

    // ---- attention (MFMA) + fusion + pooling + classifier ----
    gemm_mfma_k<1><<<gx64, 256, 0, stream>>>(h0, qwHi, qwLo, q_b, qbuf, N, 128);
    gemm_mfma_k<0><<<gx64, 256, 0, stream>>>(qbuf, kwHi, kwLo, nullptr, ubuf, N, 128);
    fusion_k<<<rb, 256, 0, stream>>>(hf, qbuf, ubuf, k_b, fused, N);
    pool_k<<<64, 256, 0, stream>>>(fused, batch, poolMean, poolMax, N);
    classifier_k<<<64, 256, 0, stream>>>(
        poolMean, poolMax, c1w, c1b, c2w, c2b, c3w, c3b, out);
}